// Round 25
// baseline (45.334 us; speedup 1.0000x reference)
//
#include <hip/hip_runtime.h>

#define KC   21      // num classes
#define BB   8       // batch
#define CC   256     // feat channels
#define HWP  65536   // 256*256 output pixels per image
#define SRC  4096    // 64*64 source pixels
#define NS   32      // chunks: TWO full source rows (128 p) each
#define PC   128     // p per chunk

// d_ws float layout: partialw [0, 5376) | partial @ 8192 ([B][NS][K][C]).
// No L map, no counts, no pre-zeroing: every buffer fully written each call.
#define WSF_PART 8192

// ---- kf: FUSED classify + gather + contraction -------------------------------
// Block (s,b): rows {2s,2s+1} = 128 p, 1024 threads, 1 block/CU x 16 waves.
// Gather phase computes argmax INLINE over the 12-row influence zone
// (21 coalesced 256B preds loads per wave per col-group) -- k1 and the L
// round-trip eliminated. feats loads issue first and hide under the gather.
// Contraction/combine/stores identical to R23 (best, 31.8us).
__global__ __launch_bounds__(1024, 4)
void kf_fused(const float* __restrict__ preds,     // [B][K][256][256]
              const int*   __restrict__ masks,     // [B][256][256]
              const float* __restrict__ feats,     // [B][C][SRC]
              float* __restrict__ partial,         // [B][NS][K][C]
              float* __restrict__ partialw)        // [B][NS][K]
{
    __shared__ float ws[KC * PC];         // [21][128] = 10.5 KB gather target
    __shared__ float scr[3 * KC * CC];    // 64.5 KB psub-combine scratch
    int s = blockIdx.x, b = blockIdx.y;   // s = 2-row chunk (rows 2s, 2s+1)
    int tid = threadIdx.x;                // 0..1023
    int p0 = s * PC;
    int ybase = 2 * s;

    int cp   = tid & 255;                 // channel
    int psub = tid >> 8;                  // wave-uniform p-quarter (0..3)
    int pw   = psub * 32;

    for (int t = tid; t < KC * PC / 4; t += 1024)     // zero ws: 672 float4
        *reinterpret_cast<float4*>(ws + t * 4) = make_float4(0.f, 0.f, 0.f, 0.f);

    // feats: own 32-p quarter straight to registers (hidden under gather)
    float f[32];
    {
        const float* frow = feats + (size_t)(b * CC + cp) * SRC + p0 + pw;
#pragma unroll
        for (int q = 0; q < 8; ++q) {
            float4 t = *reinterpret_cast<const float4*>(frow + q * 4);
            f[q * 4 + 0] = t.x; f[q * 4 + 1] = t.y;
            f[q * 4 + 2] = t.z; f[q * 4 + 3] = t.w;
        }
    }
    __syncthreads();                      // ws zeroed

    // fused classify+gather: 12 hi-res rows [8s-2, 8s+9] x 256 cols
    {
        int r = tid >> 6, cb = tid & 63;  // 16 wave-groups; r < 12 active
        int h = 8 * s - 2 + r;
        if (r < 12 && (unsigned)h < 256u) {
            float sy = h * 0.25f - 0.375f;
            int   yt = (int)floorf(sy);
            float wy = sy - (float)yt;
            int ya = yt < 0 ? 0 : yt;
            int yb = yt + 1 > 63 ? 63 : yt + 1;
            float wyy0 = ((ya == ybase)     ? (1.f - wy) : 0.f) + ((yb == ybase)     ? wy : 0.f);
            float wyy1 = ((ya == ybase + 1) ? (1.f - wy) : 0.f) + ((yb == ybase + 1) ? wy : 0.f);
            if (wyy0 != 0.f || wyy1 != 0.f) {
                const float* prow = preds + (size_t)b * KC * HWP + ((size_t)h << 8);
                const int*   mrow = masks + ((size_t)b << 16) + ((size_t)h << 8);
#pragma unroll 1
                for (int j = 0; j < 4; ++j) {
                    int w = cb + j * 64;              // lanes -> consecutive cols
                    float v[KC];
#pragma unroll
                    for (int k = 0; k < KC; ++k)      // 21 coalesced 256B loads
                        v[k] = prow[(size_t)k * HWP + w];
                    int m = mrow[w];

                    float best = v[0];
                    int   bi   = 0;
#pragma unroll
                    for (int k = 1; k < KC; ++k) {
                        if (v[k] > best) { best = v[k]; bi = k; }  // first-index ties
                    }
                    if (m == bi) {                    // implies m in [0,21)
                        float sx = w * 0.25f - 0.375f;
                        int   xt = (int)floorf(sx);
                        float wx = sx - (float)xt;
                        int xa = xt < 0 ? 0 : xt;
                        int xb = xt + 1 > 63 ? 63 : xt + 1;
                        float* wk = ws + bi * PC;
                        if (wyy0 != 0.f) {                       // row 2s
                            atomicAdd(wk + xa, wyy0 * (1.f - wx));   // dyadic-exact
                            atomicAdd(wk + xb, wyy0 * wx);
                        }
                        if (wyy1 != 0.f) {                       // row 2s+1
                            atomicAdd(wk + 64 + xa, wyy1 * (1.f - wx));
                            atomicAdd(wk + 64 + xb, wyy1 * wx);
                        }
                    }
                }
            }
        }
    }
    __syncthreads();                      // ws final

    // exact per-chunk class-count contribution (rotated reads; dyadic-exact)
    if (tid < KC) {
        float swcnt = 0.f;
#pragma unroll
        for (int i = 0; i < PC; ++i)
            swcnt += ws[tid * PC + ((i + tid * 8) & (PC - 1))];
        partialw[(size_t)(b * NS + s) * KC + tid] = swcnt;
    }

    float acc[KC];
#pragma unroll
    for (int k = 0; k < KC; ++k) {        // fully unrolled, static idx
        const float* wk = ws + k * PC + pw;
        float a0 = 0.f, a1 = 0.f, a2 = 0.f, a3 = 0.f;
#pragma unroll
        for (int q = 0; q < 8; ++q) {
            float4 w4 = *reinterpret_cast<const float4*>(wk + q * 4);  // uniform b128
            a0 += w4.x * f[q * 4 + 0];
            a1 += w4.y * f[q * 4 + 1];
            a2 += w4.z * f[q * 4 + 2];
            a3 += w4.w * f[q * 4 + 3];
        }
        acc[k] = (a0 + a1) + (a2 + a3);
    }

    // 4-way psub combine: psub 1..3 park in scr, psub0 sums and stores
    if (psub >= 1) {
        float* sp = scr + (psub - 1) * (KC * CC);
#pragma unroll
        for (int k = 0; k < KC; ++k) sp[k * CC + cp] = acc[k];
    }
    __syncthreads();
    if (psub == 0) {
        float* op = partial + ((size_t)(b * NS + s)) * KC * CC + cp;
#pragma unroll
        for (int k = 0; k < KC; ++k) {
            float v = acc[k] + scr[k * CC + cp]
                             + scr[KC * CC + k * CC + cp]
                             + scr[2 * KC * CC + k * CC + cp];
            op[(size_t)k * CC] = v;       // coalesced 1KB store per k
        }
    }
}

// ---- k3: reduce chunks + batch, normalize, single write (no atomics) --------
__global__ __launch_bounds__(256)
void k3_finalize(const float* __restrict__ partial,   // [B][NS][K][C]
                 const float* __restrict__ partialw,  // [B][NS][K]
                 float* __restrict__ out)             // [K][C]
{
    int k = blockIdx.x;    // 21
    int c = threadIdx.x;   // 256

    float r = 0.f;
#pragma unroll 1
    for (int b = 0; b < BB; ++b) {
        float cnt = 0.f;
#pragma unroll
        for (int s = 0; s < NS; ++s)              // uniform scalar loads
            cnt += partialw[(size_t)(b * NS + s) * KC + k];

        float acc = 0.f;
        const float* base = partial + ((size_t)(b * NS) * KC + k) * CC + c;
#pragma unroll 8
        for (int s = 0; s < NS; ++s) acc += base[(size_t)s * KC * CC];

        r += acc / (cnt + 1e-6f);
    }
    out[k * CC + c] = r * 0.125f;                 // written once, deterministic
}

extern "C" void kernel_launch(void* const* d_in, const int* in_sizes, int n_in,
                              void* d_out, int out_size, void* d_ws, size_t ws_size,
                              hipStream_t stream) {
    const float* feats = (const float*)d_in[0];   // [8,256,64,64]
    const float* preds = (const float*)d_in[1];   // [8,21,256,256]
    const int*   masks = (const int*)  d_in[2];   // [8,256,256]
    float* out = (float*)d_out;                   // [21,256]

    float* wsf = (float*)d_ws;
    float* partialw = wsf;                        // 5376 floats
    float* partial  = wsf + WSF_PART;             // 1376256 floats (5.5 MB)

    kf_fused<<<dim3(NS, BB), 1024, 0, stream>>>(preds, masks, feats, partial, partialw);
    k3_finalize<<<KC, 256, 0, stream>>>(partial, partialw, out);
}

// Round 26
// 32.439 us; speedup vs baseline: 1.3975x; 1.3975x over previous
//
#include <hip/hip_runtime.h>

#define KC   21      // num classes
#define BB   8       // batch
#define CC   256     // feat channels
#define HWP  65536   // 256*256 output pixels per image
#define SRC  4096    // 64*64 source pixels
#define NS   32      // chunks: TWO full source rows (128 p) each
#define PC   128     // p per chunk

// d_ws layout: L = 524288 BYTES [0, 524288) | partialw f32 @ byte 524288
// (8*32*21 = 5376 floats) | partial f32 @ float idx 139264 (5.5 MB). Disjoint.
#define WSF_PARTW 131072
#define WSF_PART  139264

// ---- k1: per-pixel argmax + gt-match -> label map (proven) ------------------
__global__ __launch_bounds__(256, 2)
void k1_classify(const float* __restrict__ preds,
                 const int*   __restrict__ masks,
                 unsigned char* __restrict__ L,
                 float* __restrict__ out)
{
    int tid = threadIdx.x;
    if (blockIdx.x == 0) {
        float4* o4 = reinterpret_cast<float4*>(out);
#pragma unroll
        for (int i = 0; i < (KC * CC / 4 + 255) / 256; ++i) {
            int j = tid + i * 256;
            if (j < KC * CC / 4) o4[j] = make_float4(0.f, 0.f, 0.f, 0.f);
        }
    }

    int idx = blockIdx.x * 256 + tid;            // over B*HWP/4 = 131072
    int b   = idx >> 14;
    int hw4 = (idx & 16383) << 2;

    const float* pb = preds + (size_t)b * KC * HWP + hw4;
    float va[4][KC];
#pragma unroll
    for (int k = 0; k < KC; ++k) {
        float4 t = *reinterpret_cast<const float4*>(pb + (size_t)k * HWP);
        va[0][k] = t.x; va[1][k] = t.y; va[2][k] = t.z; va[3][k] = t.w;
    }

    int4 mm = *reinterpret_cast<const int4*>(masks + b * HWP + hw4);
    int mk[4] = { mm.x, mm.y, mm.z, mm.w };

    uchar4 r;
    unsigned char* rp = reinterpret_cast<unsigned char*>(&r);
#pragma unroll
    for (int j = 0; j < 4; ++j) {
        float best = va[j][0];
        int   bi   = 0;
#pragma unroll
        for (int k = 1; k < KC; ++k) {
            if (va[j][k] > best) { best = va[j][k]; bi = k; }  // first-index ties
        }
        rp[j] = (mk[j] == bi) ? (unsigned char)bi : (unsigned char)255;
    }
    *reinterpret_cast<uchar4*>(L + (size_t)b * HWP + hw4) = r;
}

// ---- k2: 2-row chunks, 1024 thr, partial 5.5 MB at 16 waves/CU (R23 best) ---
__global__ __launch_bounds__(1024, 4)
void k2_contract(const float* __restrict__ feats,      // [B][C][SRC]
                 const unsigned char* __restrict__ L,  // [B][256][256]
                 float* __restrict__ partial,          // [B][NS][K][C] f32
                 float* __restrict__ partialw)         // [B][NS][K]
{
    __shared__ float ws[KC * PC];         // [21][128] = 10.5 KB gather target
    __shared__ float scr[3 * KC * CC];    // 64.5 KB psub-combine scratch
    int s = blockIdx.x, b = blockIdx.y;   // s = 2-row chunk (rows 2s, 2s+1)
    int tid = threadIdx.x;                // 0..1023
    int p0 = s * PC;
    int ybase = 2 * s;

    int cp   = tid & 255;                 // channel
    int psub = tid >> 8;                  // wave-uniform p-quarter (0..3)
    int pw   = psub * 32;

    for (int t = tid; t < KC * PC / 4; t += 1024)     // zero ws: 672 float4
        *reinterpret_cast<float4*>(ws + t * 4) = make_float4(0.f, 0.f, 0.f, 0.f);

    // feats: own 32-p quarter straight to registers (hidden under gather)
    float f[32];
    {
        const float* frow = feats + (size_t)(b * CC + cp) * SRC + p0 + pw;
#pragma unroll
        for (int q = 0; q < 8; ++q) {
            float4 t = *reinterpret_cast<const float4*>(frow + q * 4);
            f[q * 4 + 0] = t.x; f[q * 4 + 1] = t.y;
            f[q * 4 + 2] = t.z; f[q * 4 + 3] = t.w;
        }
    }
    __syncthreads();                      // ws zeroed

    // gather labels: 12 hi-res rows [8s-2, 8s+9] x 256 cols
    {
        int r = tid >> 6, cb = tid & 63;  // 16 groups x 64 threads; use r < 12
        int h = 8 * s - 2 + r;
        if (r < 12 && (unsigned)h < 256u) {
            float sy = h * 0.25f - 0.375f;
            int   yt = (int)floorf(sy);
            float wy = sy - (float)yt;
            int ya = yt < 0 ? 0 : yt;
            int yb = yt + 1 > 63 ? 63 : yt + 1;
            float wyy0 = ((ya == ybase)     ? (1.f - wy) : 0.f) + ((yb == ybase)     ? wy : 0.f);
            float wyy1 = ((ya == ybase + 1) ? (1.f - wy) : 0.f) + ((yb == ybase + 1) ? wy : 0.f);
            if (wyy0 != 0.f || wyy1 != 0.f) {
                const unsigned char* Lrow = L + ((size_t)b << 16) + ((size_t)h << 8);
#pragma unroll
                for (int j = 0; j < 4; ++j) {
                    int w = cb + j * 64;              // all 256 cols
                    int k = Lrow[w];
                    if (k < KC) {
                        float sx = w * 0.25f - 0.375f;
                        int   xt = (int)floorf(sx);
                        float wx = sx - (float)xt;
                        int xa = xt < 0 ? 0 : xt;
                        int xb = xt + 1 > 63 ? 63 : xt + 1;
                        float* wk = ws + k * PC;
                        if (wyy0 != 0.f) {                       // row 2s
                            atomicAdd(wk + xa, wyy0 * (1.f - wx));   // dyadic-exact
                            atomicAdd(wk + xb, wyy0 * wx);
                        }
                        if (wyy1 != 0.f) {                       // row 2s+1
                            atomicAdd(wk + 64 + xa, wyy1 * (1.f - wx));
                            atomicAdd(wk + 64 + xb, wyy1 * wx);
                        }
                    }
                }
            }
        }
    }
    __syncthreads();                      // ws final

    // exact per-chunk class-count contribution (rotated reads)
    float swcnt = 0.f;
    if (tid < KC) {
#pragma unroll
        for (int i = 0; i < PC; ++i)
            swcnt += ws[tid * PC + ((i + tid * 8) & (PC - 1))];
    }

    float acc[KC];
#pragma unroll
    for (int k = 0; k < KC; ++k) {        // fully unrolled, static idx
        const float* wk = ws + k * PC + pw;
        float a0 = 0.f, a1 = 0.f, a2 = 0.f, a3 = 0.f;
#pragma unroll
        for (int q = 0; q < 8; ++q) {
            float4 w4 = *reinterpret_cast<const float4*>(wk + q * 4);  // uniform b128
            a0 += w4.x * f[q * 4 + 0];
            a1 += w4.y * f[q * 4 + 1];
            a2 += w4.z * f[q * 4 + 2];
            a3 += w4.w * f[q * 4 + 3];
        }
        acc[k] = (a0 + a1) + (a2 + a3);
    }

    // 4-way psub combine: psub 1..3 park in scr, psub0 sums and stores
    if (psub >= 1) {
        float* sp = scr + (psub - 1) * (KC * CC);
#pragma unroll
        for (int k = 0; k < KC; ++k) sp[k * CC + cp] = acc[k];
    }
    __syncthreads();
    if (psub == 0) {
        float* op = partial + ((size_t)(b * NS + s)) * KC * CC + cp;
#pragma unroll
        for (int k = 0; k < KC; ++k) {
            float v = acc[k] + scr[k * CC + cp]
                             + scr[KC * CC + k * CC + cp]
                             + scr[2 * KC * CC + k * CC + cp];
            op[(size_t)k * CC] = v;       // coalesced 1KB store per k
        }
    }

    if (tid < KC)
        partialw[(size_t)(b * NS + s) * KC + tid] = swcnt;  // dyadic-exact
}

// ---- k3: reduce 32 chunks, derive exact counts, normalize -------------------
__global__ __launch_bounds__(256)
void k3_finalize(const float* __restrict__ partial,   // [B][NS][K][C]
                 const float* __restrict__ partialw,  // [B][NS][K]
                 float* __restrict__ out)             // [K][C], zeroed by k1
{
    int k = blockIdx.x, b = blockIdx.y;
    int tid = threadIdx.x;

    const float* base = partial + ((size_t)(b * NS) * KC + k) * CC + tid;
    float acc = 0.f;
#pragma unroll 8
    for (int s = 0; s < NS; ++s) acc += base[(size_t)s * KC * CC];

    __shared__ float red;
    if (tid < 64) {                       // single-wave reduce of 32 counts
        float v = (tid < NS) ? partialw[(size_t)(b * NS + tid) * KC + k] : 0.f;
#pragma unroll
        for (int off = 32; off; off >>= 1) v += __shfl_down(v, off);
        if (tid == 0) red = v;
    }
    __syncthreads();
    float cnt = red;                      // dyadic-exact pixel count

    atomicAdd(&out[k * CC + tid], acc / (8.f * (cnt + 1e-6f)));
}

extern "C" void kernel_launch(void* const* d_in, const int* in_sizes, int n_in,
                              void* d_out, int out_size, void* d_ws, size_t ws_size,
                              hipStream_t stream) {
    const float* feats = (const float*)d_in[0];   // [8,256,64,64]
    const float* preds = (const float*)d_in[1];   // [8,21,256,256]
    const int*   masks = (const int*)  d_in[2];   // [8,256,256]
    float* out = (float*)d_out;                   // [21,256]

    float* wsf = (float*)d_ws;
    unsigned char* L = (unsigned char*)d_ws;      // 524288 bytes, fully written by k1
    float* partialw = wsf + WSF_PARTW;            // byte 524288: disjoint from L
    float* partial  = wsf + WSF_PART;

    k1_classify<<<(BB * HWP / 4) / 256, 256, 0, stream>>>(preds, masks, L, out);
    k2_contract<<<dim3(NS, BB), 1024, 0, stream>>>(feats, L, partial, partialw);
    k3_finalize<<<dim3(KC, BB), 256, 0, stream>>>(partial, partialw, out);
}